// Round 14
// baseline (1394.665 us; speedup 1.0000x reference)
//
#include <hip/hip_runtime.h>

// SiameseClassifier: twin LSTM (shared weights) over T=128 steps, B=128 each,
// E=H=1024, V=32000. out[b] = exp(-L1(h_a[b], h_b[b])).
//
// R14 = R13 + critical-path reordering:
//  - A/B it0 preloads issued FIRST (R13 issued the token->emb gather chain
//    first; the emb address depends on the token load, so the wave stalled
//    on vmcnt before issuing the GEMM's first loads).
//  - bias + c_old preloaded at kernel top (epilogue inputs hidden under GEMM).
//  - s_setprio(1) around the MFMA cluster (2 blocks/CU -> phase diversity).
//  Proven structure unchanged: grid 512 = m(8: 32-row tiles) x nh(64);
//  block 256 = 4 waves = kg(2) x wn(2); B read once per block; fp8 e4m3
//  operands (x'=16x, W'=16W); gates = Gs0/256 + Gs1/16 + bias; c fp32.

typedef unsigned char u8;
typedef unsigned short u16;
typedef unsigned long long u64;
typedef __attribute__((ext_vector_type(2))) unsigned long long u64x2;
typedef __attribute__((ext_vector_type(2))) float f32x2;
typedef __attribute__((ext_vector_type(4))) float f32x4;

// f32 -> OCP e4m3fn (RNE, saturate to 448)
__device__ __forceinline__ u8 f2e4m3(float f) {
  unsigned ui = __builtin_bit_cast(unsigned, f);
  unsigned s = (ui >> 24) & 0x80u;
  float a = fabsf(f);
  if (a >= 448.f) return (u8)(s | 0x7Eu);
  if (a < 0.015625f) {                       // denormal (incl. 0): step 2^-9
    int m = (int)rintf(a * 512.f);
    return (u8)(s | (unsigned)m);
  }
  unsigned au = ui & 0x7fffffffu;
  int e = (int)(au >> 23) - 127;
  float mm = __builtin_bit_cast(float, (au & 0x007fffffu) | 0x3f800000u);
  int q = (int)rintf((mm - 1.0f) * 8.0f);
  unsigned body = (unsigned)(((e + 7) << 3) + q);
  if (body > 0x7Eu) body = 0x7Eu;
  return (u8)(s | body);
}
__device__ __forceinline__ float e4m32f(u8 b) {
  unsigned e = (b >> 3) & 15u;
  unsigned m = b & 7u;
  float mag = (e == 0) ? (float)m * 0.001953125f
                       : __builtin_bit_cast(float, (e + 117u) << 23) * (float)(8u + m);
  return (b & 0x80u) ? -mag : mag;
}

// ---------------- prep: 16*W -> fp8, fragment order ----------------
// frag idx8 = ((nh*4 + f)*64 + kcg)*64 + lane ; 8 fp8 per idx8 (8 B)
//   element: W[f*1024 + nh*16 + (lane&15)][kcg*32 + (lane>>4)*8 + j]
__global__ __launch_bounds__(256) void prep_wf_kernel(const float* __restrict__ w_ih,
                                                      const float* __restrict__ w_hh,
                                                      u8* __restrict__ Wf) {
  unsigned idx = blockIdx.x * 256u + threadIdx.x;          // 0..1048575
  unsigned l = idx & 63u;
  unsigned kcg = (idx >> 6) & 63u;
  unsigned f = (idx >> 12) & 3u;
  unsigned nh = idx >> 14;
  unsigned r = f * 1024u + nh * 16u + (l & 15u);
  unsigned k0 = kcg * 32u + ((l >> 4) << 3);
  const float* src = (k0 < 1024u) ? (w_ih + (size_t)r * 1024u + k0)
                                  : (w_hh + (size_t)r * 1024u + (k0 - 1024u));
  float4 v0 = *(const float4*)src;
  float4 v1 = *(const float4*)(src + 4);
  u64 o = 0;
  o |= (u64)f2e4m3(v0.x * 16.f);
  o |= (u64)f2e4m3(v0.y * 16.f) << 8;
  o |= (u64)f2e4m3(v0.z * 16.f) << 16;
  o |= (u64)f2e4m3(v0.w * 16.f) << 24;
  o |= (u64)f2e4m3(v1.x * 16.f) << 32;
  o |= (u64)f2e4m3(v1.y * 16.f) << 40;
  o |= (u64)f2e4m3(v1.z * 16.f) << 48;
  o |= (u64)f2e4m3(v1.w * 16.f) << 56;
  *(u64*)(Wf + (size_t)idx * 8u) = o;
}

// ---------------- prep: state (h0 fp8, c0 fp32, x0 = 16*emb fp8) -----------
__global__ __launch_bounds__(256) void prep_state_kernel(
    const float* __restrict__ h0a, const float* __restrict__ h0b,
    const float* __restrict__ c0a, const float* __restrict__ c0b,
    const float* __restrict__ b_ih, const float* __restrict__ b_hh,
    const int* __restrict__ batch_a, const int* __restrict__ batch_b,
    const float* __restrict__ emb,
    float* __restrict__ bias, u8* __restrict__ hb0, float* __restrict__ cb,
    u8* __restrict__ xb0) {
  unsigned i = blockIdx.x * 256u + threadIdx.x;            // 0..262143
  unsigned r = i >> 10;
  unsigned k = i & 1023u;
  float hv = (r < 128u) ? h0a[i] : h0b[i - 131072u];
  float cv = (r < 128u) ? c0a[i] : c0b[i - 131072u];
  hb0[i] = f2e4m3(hv);
  cb[i] = cv;
  int token = (r < 128u) ? batch_a[r] : batch_b[r - 128u];
  xb0[i] = f2e4m3(emb[(size_t)token * 1024u + k] * 16.f);
  if (i < 4096u) bias[i] = b_ih[i] + b_hh[i];
}

// ---------------- the recurrent step ----------------
// grid 512 = m(8: 32-row tiles) x nh(64: 16 h-units = 64 gatecols).
// block 256 = 4 waves: kg(2 K-halves) x wn(2 fc-pairs); acc[2 frg][2 fc].
__global__ __launch_bounds__(256) void lstm_step_kernel(
    const int* __restrict__ batch_a, const int* __restrict__ batch_b,
    const float* __restrict__ emb, const u8* __restrict__ Wf,
    const float* __restrict__ bias,
    const u8* __restrict__ x_in, u8* __restrict__ x_next,
    const u8* __restrict__ h_in, u8* __restrict__ h_out,
    float* __restrict__ cbuf, int t) {
  __shared__ u8 As[2][2][32][128];    // [kg][buf][row][kB] 16 KB, swizzled rows
  __shared__ float Gs[2][32][68];     // [kg][row][gatecol] 17.4 KB partials

  const int tid = threadIdx.x;
  const int lane = tid & 63;
  const int w = tid >> 6;
  const int kg = w >> 1, wn = w & 1;
  const int m = blockIdx.x >> 6;      // 0..7
  const int nh = blockIdx.x & 63;

  // ---- staging map: tid<128 stages kg0 (x), tid>=128 kg1 (h) ----
  const int skg = tid >> 7;
  const int gtid = tid & 127;
  const int srow = gtid >> 2;          // 0..31
  const int q32 = (gtid & 3) << 5;     // byte 0,32,64,96 within 128B it-chunk
  const int wswz = (srow & 15) << 3;   // write swizzle (bytes)
  char* dstA0 = (char*)&As[skg][0][0][0] + srow * 128;
  char* dstA1 = (char*)&As[skg][1][0][0] + srow * 128;
  const u8* aBase = (skg == 0 ? x_in : h_in)
                    + ((size_t)(m * 32 + srow) << 10) + q32;

  // ---- B fragment bases (fragment-ordered fp8 Wf; 512 B per frag) ----
  const u8* wf0 = Wf + ((((size_t)(nh * 4 + wn * 2) * 64) + kg * 32) << 9) + lane * 8;
  const u8* wf1 = wf0 + (64 << 9);

  // ---- GEMM it0 preloads FIRST (critical path) ----
  u64x2 av[2];
  u64 brc[8], brn[8];
  av[0] = *(const u64x2*)(aBase);
  av[1] = *(const u64x2*)(aBase + 16);
#pragma unroll
  for (int kcl = 0; kcl < 4; ++kcl) {
    brc[kcl * 2]     = *(const u64*)(wf0 + (kcl << 9));
    brc[kcl * 2 + 1] = *(const u64*)(wf1 + (kcl << 9));
  }

  // ---- epilogue inputs preloaded here: hidden under the GEMM ----
  const int crow = tid >> 3;           // 0..31
  const int u0 = (tid & 7) << 1;       // unit pair
  const int R2e = m * 32 + crow;
  const int gje = nh * 16 + u0;
  const size_t cie = (size_t)R2e * 1024 + gje;
  f32x2 c_old = *(const f32x2*)(cbuf + cie);
  f32x2 bi = *(const f32x2*)(bias + gje);
  f32x2 bf = *(const f32x2*)(bias + 1024 + gje);
  f32x2 bg = *(const f32x2*)(bias + 2048 + gje);
  f32x2 bo = *(const f32x2*)(bias + 3072 + gje);

  // ---- x_{t+1} gather LAST (dependent chain token->emb, consumed at end) --
  f32x4 g0 = {0.f, 0.f, 0.f, 0.f};
  const bool do_g = (t + 1 < 128) && (tid < 128);
  if (do_g) {
    int r = blockIdx.x >> 1;          // 0..255
    int half = blockIdx.x & 1;
    int token = (r < 128) ? batch_a[(t + 1) * 128 + r]
                          : batch_b[(t + 1) * 128 + (r - 128)];
    g0 = __builtin_nontemporal_load(
        (const f32x4*)(emb + (size_t)token * 1024 + half * 512 + tid * 4));
  }

  // ---- fragment read ids ----
  const int fr = lane & 15;
  const int fkb = (lane >> 4) << 3;    // byte 0,8,16,24
  const int rswz = fr << 3;            // (row&15)<<3, same for both row-frags
  const char* A0 = (const char*)&As[kg][0][0][0];
  const char* A1 = (const char*)&As[kg][1][0][0];

  f32x4 acc[2][2];
#pragma unroll
  for (int a_ = 0; a_ < 2; ++a_)
#pragma unroll
    for (int b_ = 0; b_ < 2; ++b_) acc[a_][b_] = (f32x4){0.f, 0.f, 0.f, 0.f};

#pragma unroll
  for (int it = 0; it < 8; ++it) {
    {  // stage A it-chunk (swizzled; bank-floor map)
      char* dst = (it & 1) ? dstA1 : dstA0;
      *(u64*)(dst + ((q32 + 0)  ^ wswz)) = av[0][0];
      *(u64*)(dst + ((q32 + 8)  ^ wswz)) = av[0][1];
      *(u64*)(dst + ((q32 + 16) ^ wswz)) = av[1][0];
      *(u64*)(dst + ((q32 + 24) ^ wswz)) = av[1][1];
    }
    __syncthreads();
    if (it < 7) {  // prefetch next A chunk + next B frags
      const u8* an = aBase + (it + 1) * 128;
      av[0] = *(const u64x2*)(an);
      av[1] = *(const u64x2*)(an + 16);
#pragma unroll
      for (int kcl = 0; kcl < 4; ++kcl) {
        brn[kcl * 2]     = *(const u64*)(wf0 + (((it + 1) * 4 + kcl) << 9));
        brn[kcl * 2 + 1] = *(const u64*)(wf1 + (((it + 1) * 4 + kcl) << 9));
      }
    }
    const char* ab = (it & 1) ? A1 : A0;
    __builtin_amdgcn_s_setprio(1);
#pragma unroll
    for (int kcl = 0; kcl < 4; ++kcl) {
      long b0 = __builtin_bit_cast(long, brc[kcl * 2]);
      long b1 = __builtin_bit_cast(long, brc[kcl * 2 + 1]);
#pragma unroll
      for (int frg = 0; frg < 2; ++frg) {
        u64 afu = *(const u64*)(ab + (frg * 16 + fr) * 128 + ((kcl * 32 + fkb) ^ rswz));
        long a0 = __builtin_bit_cast(long, afu);
        acc[frg][0] = __builtin_amdgcn_mfma_f32_16x16x32_fp8_fp8(a0, b0, acc[frg][0], 0, 0, 0);
        acc[frg][1] = __builtin_amdgcn_mfma_f32_16x16x32_fp8_fp8(a0, b1, acc[frg][1], 0, 0, 0);
      }
    }
    __builtin_amdgcn_s_setprio(0);
    if (it < 7) {
#pragma unroll
      for (int p = 0; p < 8; ++p) brc[p] = brn[p];
    }
  }

  // ---- kg-partial gates to LDS (each kg its own plane), one barrier ----
  {
    const int hi4 = (lane >> 4) << 2;
#pragma unroll
    for (int frg = 0; frg < 2; ++frg)
#pragma unroll
      for (int fc = 0; fc < 2; ++fc)
#pragma unroll
        for (int r_ = 0; r_ < 4; ++r_)
          Gs[kg][frg * 16 + hi4 + r_][(wn * 2 + fc) * 16 + fr] = acc[frg][fc][r_];
  }
  __syncthreads();

  // ---- fused cell update: 2 units/thread (inputs preloaded) ----
  {
    f32x2 cnv;
    u16 pk = 0;
    const float bsv[4][2] = {{bi[0], bi[1]}, {bf[0], bf[1]}, {bg[0], bg[1]}, {bo[0], bo[1]}};
#pragma unroll
    for (int uu = 0; uu < 2; ++uu) {
      int cix = u0 + uu;
      float iv = Gs[0][crow][cix]      * 0.00390625f + Gs[1][crow][cix]      * 0.0625f + bsv[0][uu];
      float fv = Gs[0][crow][16 + cix] * 0.00390625f + Gs[1][crow][16 + cix] * 0.0625f + bsv[1][uu];
      float gv = Gs[0][crow][32 + cix] * 0.00390625f + Gs[1][crow][32 + cix] * 0.0625f + bsv[2][uu];
      float ov = Gs[0][crow][48 + cix] * 0.00390625f + Gs[1][crow][48 + cix] * 0.0625f + bsv[3][uu];
      float si = 1.f / (1.f + __expf(-iv));
      float sf = 1.f / (1.f + __expf(-fv));
      float so = 1.f / (1.f + __expf(-ov));
      float cn = sf * c_old[uu] + si * tanhf(gv);
      cnv[uu] = cn;
      float hn = so * tanhf(cn);
      pk |= ((u16)f2e4m3(hn)) << (uu * 8);
    }
    *(f32x2*)(cbuf + cie) = cnv;
    *(u16*)(h_out + cie) = pk;
  }

  // ---- store the pre-gathered x_{t+1} (16x scaled, fp8) ----
  if (do_g) {
    int r = blockIdx.x >> 1;
    int half = blockIdx.x & 1;
    unsigned o = 0;
    o |= (unsigned)f2e4m3(g0[0] * 16.f);
    o |= (unsigned)f2e4m3(g0[1] * 16.f) << 8;
    o |= (unsigned)f2e4m3(g0[2] * 16.f) << 16;
    o |= (unsigned)f2e4m3(g0[3] * 16.f) << 24;
    *(unsigned*)(x_next + (size_t)r * 1024 + half * 512 + tid * 4) = o;
  }
}

// ---------------- finalize (fp8 h) ----------------
__global__ __launch_bounds__(256) void finalize_kernel(const u8* __restrict__ h,
                                                       float* __restrict__ out) {
  int b = blockIdx.x;
  int tid = threadIdx.x;
  const u8* ha = h + (size_t)b * 1024;
  const u8* hb = h + (size_t)(b + 128) * 1024;
  float s = 0.f;
  for (int j = tid; j < 1024; j += 256) s += fabsf(e4m32f(ha[j]) - e4m32f(hb[j]));
  __shared__ float red[256];
  red[tid] = s;
  __syncthreads();
  for (int off = 128; off > 0; off >>= 1) {
    if (tid < off) red[tid] += red[tid + off];
    __syncthreads();
  }
  if (tid == 0) out[b] = expf(-red[0]);
}

extern "C" void kernel_launch(void* const* d_in, const int* in_sizes, int n_in,
                              void* d_out, int out_size, void* d_ws, size_t ws_size,
                              hipStream_t stream) {
  const int* batch_a = (const int*)d_in[0];
  const int* batch_b = (const int*)d_in[1];
  const float* h0_a = (const float*)d_in[2];
  const float* c0_a = (const float*)d_in[3];
  const float* h0_b = (const float*)d_in[4];
  const float* c0_b = (const float*)d_in[5];
  const float* emb  = (const float*)d_in[6];
  const float* w_ih = (const float*)d_in[7];
  const float* w_hh = (const float*)d_in[8];
  const float* b_ih = (const float*)d_in[9];
  const float* b_hh = (const float*)d_in[10];

  char* ws = (char*)d_ws;
  u8*    Wf   = (u8*)(ws);                     //  8,388,608 B
  float* bias = (float*)(ws + 8388608);        //     16,384 B
  u8*    xb0  = (u8*)(ws + 8404992);           //    262,144 B
  u8*    xb1  = (u8*)(ws + 8667136);           //    262,144 B
  u8*    hb0  = (u8*)(ws + 8929280);           //    262,144 B
  u8*    hb1  = (u8*)(ws + 9191424);           //    262,144 B
  float* cb   = (float*)(ws + 9453568);        //  1,048,576 B (end ~10.5 MB)

  prep_wf_kernel<<<4096, 256, 0, stream>>>(w_ih, w_hh, Wf);
  prep_state_kernel<<<1024, 256, 0, stream>>>(h0_a, h0_b, c0_a, c0_b, b_ih, b_hh,
                                              batch_a, batch_b, emb, bias, hb0, cb, xb0);
  u8* xb[2] = {xb0, xb1};
  u8* hb[2] = {hb0, hb1};
  for (int t = 0; t < 128; ++t) {
    lstm_step_kernel<<<512, 256, 0, stream>>>(batch_a, batch_b, emb, Wf, bias,
                                              xb[t & 1], xb[(t + 1) & 1],
                                              hb[t & 1], hb[(t + 1) & 1], cb, t);
  }
  finalize_kernel<<<128, 256, 0, stream>>>(hb[0], (float*)d_out);
}

// Round 15
// 1291.894 us; speedup vs baseline: 1.0796x; 1.0796x over previous
//
#include <hip/hip_runtime.h>

// SiameseClassifier: twin LSTM (shared weights) over T=128 steps, B=128 each,
// E=H=1024, V=32000. V, E, H, T as in reference.
//
// R15 = R13 + ONE change: GEMM it0 A/B preloads issued BEFORE the dependent
// token->emb gather chain (R13 issued the gather first; its emb address
// depends on the token load). R14's other two changes (s_setprio around MFMA,
// epilogue c/bias preload hoist) are REVERTED: setprio is proven
// null-to-negative on barrier-lockstep GEMM blocks (catalog T5 / m190), and
// the preload hoist extends live ranges across the GEMM for no measured gain
// (R14 regressed 1303->1395).
//  Proven structure (R13, best=1303us): grid 512 = m(8: 32-row tiles) x
//  nh(64); block 256 = 4 waves = kg(2) x wn(2); B read once per block;
//  fp8 e4m3 operands (x'=16x, W'=16W); gates = Gs0/256 + Gs1/16 + bias;
//  c fp32; h fp8; per-step launches.

typedef unsigned char u8;
typedef unsigned short u16;
typedef unsigned long long u64;
typedef __attribute__((ext_vector_type(2))) unsigned long long u64x2;
typedef __attribute__((ext_vector_type(2))) float f32x2;
typedef __attribute__((ext_vector_type(4))) float f32x4;

// f32 -> OCP e4m3fn (RNE, saturate to 448)
__device__ __forceinline__ u8 f2e4m3(float f) {
  unsigned ui = __builtin_bit_cast(unsigned, f);
  unsigned s = (ui >> 24) & 0x80u;
  float a = fabsf(f);
  if (a >= 448.f) return (u8)(s | 0x7Eu);
  if (a < 0.015625f) {                       // denormal (incl. 0): step 2^-9
    int m = (int)rintf(a * 512.f);
    return (u8)(s | (unsigned)m);
  }
  unsigned au = ui & 0x7fffffffu;
  int e = (int)(au >> 23) - 127;
  float mm = __builtin_bit_cast(float, (au & 0x007fffffu) | 0x3f800000u);
  int q = (int)rintf((mm - 1.0f) * 8.0f);
  unsigned body = (unsigned)(((e + 7) << 3) + q);
  if (body > 0x7Eu) body = 0x7Eu;
  return (u8)(s | body);
}
__device__ __forceinline__ float e4m32f(u8 b) {
  unsigned e = (b >> 3) & 15u;
  unsigned m = b & 7u;
  float mag = (e == 0) ? (float)m * 0.001953125f
                       : __builtin_bit_cast(float, (e + 117u) << 23) * (float)(8u + m);
  return (b & 0x80u) ? -mag : mag;
}

// ---------------- prep: 16*W -> fp8, fragment order ----------------
// frag idx8 = ((nh*4 + f)*64 + kcg)*64 + lane ; 8 fp8 per idx8 (8 B)
//   element: W[f*1024 + nh*16 + (lane&15)][kcg*32 + (lane>>4)*8 + j]
__global__ __launch_bounds__(256) void prep_wf_kernel(const float* __restrict__ w_ih,
                                                      const float* __restrict__ w_hh,
                                                      u8* __restrict__ Wf) {
  unsigned idx = blockIdx.x * 256u + threadIdx.x;          // 0..1048575
  unsigned l = idx & 63u;
  unsigned kcg = (idx >> 6) & 63u;
  unsigned f = (idx >> 12) & 3u;
  unsigned nh = idx >> 14;
  unsigned r = f * 1024u + nh * 16u + (l & 15u);
  unsigned k0 = kcg * 32u + ((l >> 4) << 3);
  const float* src = (k0 < 1024u) ? (w_ih + (size_t)r * 1024u + k0)
                                  : (w_hh + (size_t)r * 1024u + (k0 - 1024u));
  float4 v0 = *(const float4*)src;
  float4 v1 = *(const float4*)(src + 4);
  u64 o = 0;
  o |= (u64)f2e4m3(v0.x * 16.f);
  o |= (u64)f2e4m3(v0.y * 16.f) << 8;
  o |= (u64)f2e4m3(v0.z * 16.f) << 16;
  o |= (u64)f2e4m3(v0.w * 16.f) << 24;
  o |= (u64)f2e4m3(v1.x * 16.f) << 32;
  o |= (u64)f2e4m3(v1.y * 16.f) << 40;
  o |= (u64)f2e4m3(v1.z * 16.f) << 48;
  o |= (u64)f2e4m3(v1.w * 16.f) << 56;
  *(u64*)(Wf + (size_t)idx * 8u) = o;
}

// ---------------- prep: state (h0 fp8, c0 fp32, x0 = 16*emb fp8) -----------
__global__ __launch_bounds__(256) void prep_state_kernel(
    const float* __restrict__ h0a, const float* __restrict__ h0b,
    const float* __restrict__ c0a, const float* __restrict__ c0b,
    const float* __restrict__ b_ih, const float* __restrict__ b_hh,
    const int* __restrict__ batch_a, const int* __restrict__ batch_b,
    const float* __restrict__ emb,
    float* __restrict__ bias, u8* __restrict__ hb0, float* __restrict__ cb,
    u8* __restrict__ xb0) {
  unsigned i = blockIdx.x * 256u + threadIdx.x;            // 0..262143
  unsigned r = i >> 10;
  unsigned k = i & 1023u;
  float hv = (r < 128u) ? h0a[i] : h0b[i - 131072u];
  float cv = (r < 128u) ? c0a[i] : c0b[i - 131072u];
  hb0[i] = f2e4m3(hv);
  cb[i] = cv;
  int token = (r < 128u) ? batch_a[r] : batch_b[r - 128u];
  xb0[i] = f2e4m3(emb[(size_t)token * 1024u + k] * 16.f);
  if (i < 4096u) bias[i] = b_ih[i] + b_hh[i];
}

// ---------------- the recurrent step ----------------
// grid 512 = m(8: 32-row tiles) x nh(64: 16 h-units = 64 gatecols).
// block 256 = 4 waves: kg(2 K-halves) x wn(2 fc-pairs); acc[2 frg][2 fc].
__global__ __launch_bounds__(256) void lstm_step_kernel(
    const int* __restrict__ batch_a, const int* __restrict__ batch_b,
    const float* __restrict__ emb, const u8* __restrict__ Wf,
    const float* __restrict__ bias,
    const u8* __restrict__ x_in, u8* __restrict__ x_next,
    const u8* __restrict__ h_in, u8* __restrict__ h_out,
    float* __restrict__ cbuf, int t) {
  __shared__ u8 As[2][2][32][128];    // [kg][buf][row][kB] 16 KB, swizzled rows
  __shared__ float Gs[2][32][68];     // [kg][row][gatecol] 17.4 KB partials

  const int tid = threadIdx.x;
  const int lane = tid & 63;
  const int w = tid >> 6;
  const int kg = w >> 1, wn = w & 1;
  const int m = blockIdx.x >> 6;      // 0..7
  const int nh = blockIdx.x & 63;

  // ---- staging map: tid<128 stages kg0 (x), tid>=128 kg1 (h) ----
  const int skg = tid >> 7;
  const int gtid = tid & 127;
  const int srow = gtid >> 2;          // 0..31
  const int q32 = (gtid & 3) << 5;     // byte 0,32,64,96 within 128B it-chunk
  const int wswz = (srow & 15) << 3;   // write swizzle (bytes)
  char* dstA0 = (char*)&As[skg][0][0][0] + srow * 128;
  char* dstA1 = (char*)&As[skg][1][0][0] + srow * 128;
  const u8* aBase = (skg == 0 ? x_in : h_in)
                    + ((size_t)(m * 32 + srow) << 10) + q32;

  // ---- B fragment bases (fragment-ordered fp8 Wf; 512 B per frag) ----
  const u8* wf0 = Wf + ((((size_t)(nh * 4 + wn * 2) * 64) + kg * 32) << 9) + lane * 8;
  const u8* wf1 = wf0 + (64 << 9);

  // ---- GEMM it0 preloads FIRST (before the dependent gather chain) ----
  u64x2 av[2];
  u64 brc[8], brn[8];
  av[0] = *(const u64x2*)(aBase);
  av[1] = *(const u64x2*)(aBase + 16);
#pragma unroll
  for (int kcl = 0; kcl < 4; ++kcl) {
    brc[kcl * 2]     = *(const u64*)(wf0 + (kcl << 9));
    brc[kcl * 2 + 1] = *(const u64*)(wf1 + (kcl << 9));
  }

  // ---- x_{t+1} gather (dependent chain token->emb; consumed at end) ----
  f32x4 g0 = {0.f, 0.f, 0.f, 0.f};
  const bool do_g = (t + 1 < 128) && (tid < 128);
  if (do_g) {
    int r = blockIdx.x >> 1;          // 0..255
    int half = blockIdx.x & 1;
    int token = (r < 128) ? batch_a[(t + 1) * 128 + r]
                          : batch_b[(t + 1) * 128 + (r - 128)];
    g0 = __builtin_nontemporal_load(
        (const f32x4*)(emb + (size_t)token * 1024 + half * 512 + tid * 4));
  }

  // ---- fragment read ids ----
  const int fr = lane & 15;
  const int fkb = (lane >> 4) << 3;    // byte 0,8,16,24
  const int rswz = fr << 3;            // (row&15)<<3, same for both row-frags
  const char* A0 = (const char*)&As[kg][0][0][0];
  const char* A1 = (const char*)&As[kg][1][0][0];

  f32x4 acc[2][2];
#pragma unroll
  for (int a_ = 0; a_ < 2; ++a_)
#pragma unroll
    for (int b_ = 0; b_ < 2; ++b_) acc[a_][b_] = (f32x4){0.f, 0.f, 0.f, 0.f};

#pragma unroll
  for (int it = 0; it < 8; ++it) {
    {  // stage A it-chunk (swizzled; write at 4-lane/bank-pair floor)
      char* dst = (it & 1) ? dstA1 : dstA0;
      *(u64*)(dst + ((q32 + 0)  ^ wswz)) = av[0][0];
      *(u64*)(dst + ((q32 + 8)  ^ wswz)) = av[0][1];
      *(u64*)(dst + ((q32 + 16) ^ wswz)) = av[1][0];
      *(u64*)(dst + ((q32 + 24) ^ wswz)) = av[1][1];
    }
    __syncthreads();
    if (it < 7) {  // prefetch next A chunk + next B frags
      const u8* an = aBase + (it + 1) * 128;
      av[0] = *(const u64x2*)(an);
      av[1] = *(const u64x2*)(an + 16);
#pragma unroll
      for (int kcl = 0; kcl < 4; ++kcl) {
        brn[kcl * 2]     = *(const u64*)(wf0 + (((it + 1) * 4 + kcl) << 9));
        brn[kcl * 2 + 1] = *(const u64*)(wf1 + (((it + 1) * 4 + kcl) << 9));
      }
    }
    const char* ab = (it & 1) ? A1 : A0;
#pragma unroll
    for (int kcl = 0; kcl < 4; ++kcl) {
      long b0 = __builtin_bit_cast(long, brc[kcl * 2]);
      long b1 = __builtin_bit_cast(long, brc[kcl * 2 + 1]);
#pragma unroll
      for (int frg = 0; frg < 2; ++frg) {
        u64 afu = *(const u64*)(ab + (frg * 16 + fr) * 128 + ((kcl * 32 + fkb) ^ rswz));
        long a0 = __builtin_bit_cast(long, afu);
        acc[frg][0] = __builtin_amdgcn_mfma_f32_16x16x32_fp8_fp8(a0, b0, acc[frg][0], 0, 0, 0);
        acc[frg][1] = __builtin_amdgcn_mfma_f32_16x16x32_fp8_fp8(a0, b1, acc[frg][1], 0, 0, 0);
      }
    }
    if (it < 7) {
#pragma unroll
      for (int p = 0; p < 8; ++p) brc[p] = brn[p];
    }
  }

  // ---- kg-partial gates to LDS (each kg its own plane), one barrier ----
  {
    const int hi4 = (lane >> 4) << 2;
#pragma unroll
    for (int frg = 0; frg < 2; ++frg)
#pragma unroll
      for (int fc = 0; fc < 2; ++fc)
#pragma unroll
        for (int r_ = 0; r_ < 4; ++r_)
          Gs[kg][frg * 16 + hi4 + r_][(wn * 2 + fc) * 16 + fr] = acc[frg][fc][r_];
  }
  __syncthreads();

  // ---- fused cell update: 2 units/thread, float2 c, packed u16 h ----
  {
    const int crow = tid >> 3;          // 0..31
    const int u0 = (tid & 7) << 1;      // unit pair
    const int R2 = m * 32 + crow;
    const int gj = nh * 16 + u0;
    size_t ci = (size_t)R2 * 1024 + gj;
    f32x2 c_old = *(const f32x2*)(cbuf + ci);
    f32x2 cnv;
    u16 pk = 0;
#pragma unroll
    for (int uu = 0; uu < 2; ++uu) {
      int cix = u0 + uu;
      int gjc = gj + uu;
      float iv = Gs[0][crow][cix]      * 0.00390625f + Gs[1][crow][cix]      * 0.0625f + bias[gjc];
      float fv = Gs[0][crow][16 + cix] * 0.00390625f + Gs[1][crow][16 + cix] * 0.0625f + bias[1024 + gjc];
      float gv = Gs[0][crow][32 + cix] * 0.00390625f + Gs[1][crow][32 + cix] * 0.0625f + bias[2048 + gjc];
      float ov = Gs[0][crow][48 + cix] * 0.00390625f + Gs[1][crow][48 + cix] * 0.0625f + bias[3072 + gjc];
      float si = 1.f / (1.f + __expf(-iv));
      float sf = 1.f / (1.f + __expf(-fv));
      float so = 1.f / (1.f + __expf(-ov));
      float cn = sf * c_old[uu] + si * tanhf(gv);
      cnv[uu] = cn;
      float hn = so * tanhf(cn);
      pk |= ((u16)f2e4m3(hn)) << (uu * 8);
    }
    *(f32x2*)(cbuf + ci) = cnv;
    *(u16*)(h_out + ci) = pk;
  }

  // ---- store the pre-gathered x_{t+1} (16x scaled, fp8) ----
  if (do_g) {
    int r = blockIdx.x >> 1;
    int half = blockIdx.x & 1;
    unsigned o = 0;
    o |= (unsigned)f2e4m3(g0[0] * 16.f);
    o |= (unsigned)f2e4m3(g0[1] * 16.f) << 8;
    o |= (unsigned)f2e4m3(g0[2] * 16.f) << 16;
    o |= (unsigned)f2e4m3(g0[3] * 16.f) << 24;
    *(unsigned*)(x_next + (size_t)r * 1024 + half * 512 + tid * 4) = o;
  }
}

// ---------------- finalize (fp8 h) ----------------
__global__ __launch_bounds__(256) void finalize_kernel(const u8* __restrict__ h,
                                                       float* __restrict__ out) {
  int b = blockIdx.x;
  int tid = threadIdx.x;
  const u8* ha = h + (size_t)b * 1024;
  const u8* hb = h + (size_t)(b + 128) * 1024;
  float s = 0.f;
  for (int j = tid; j < 1024; j += 256) s += fabsf(e4m32f(ha[j]) - e4m32f(hb[j]));
  __shared__ float red[256];
  red[tid] = s;
  __syncthreads();
  for (int off = 128; off > 0; off >>= 1) {
    if (tid < off) red[tid] += red[tid + off];
    __syncthreads();
  }
  if (tid == 0) out[b] = expf(-red[0]);
}

extern "C" void kernel_launch(void* const* d_in, const int* in_sizes, int n_in,
                              void* d_out, int out_size, void* d_ws, size_t ws_size,
                              hipStream_t stream) {
  const int* batch_a = (const int*)d_in[0];
  const int* batch_b = (const int*)d_in[1];
  const float* h0_a = (const float*)d_in[2];
  const float* c0_a = (const float*)d_in[3];
  const float* h0_b = (const float*)d_in[4];
  const float* c0_b = (const float*)d_in[5];
  const float* emb  = (const float*)d_in[6];
  const float* w_ih = (const float*)d_in[7];
  const float* w_hh = (const float*)d_in[8];
  const float* b_ih = (const float*)d_in[9];
  const float* b_hh = (const float*)d_in[10];

  char* ws = (char*)d_ws;
  u8*    Wf   = (u8*)(ws);                     //  8,388,608 B
  float* bias = (float*)(ws + 8388608);        //     16,384 B
  u8*    xb0  = (u8*)(ws + 8404992);           //    262,144 B
  u8*    xb1  = (u8*)(ws + 8667136);           //    262,144 B
  u8*    hb0  = (u8*)(ws + 8929280);           //    262,144 B
  u8*    hb1  = (u8*)(ws + 9191424);           //    262,144 B
  float* cb   = (float*)(ws + 9453568);        //  1,048,576 B (end ~10.5 MB)

  prep_wf_kernel<<<4096, 256, 0, stream>>>(w_ih, w_hh, Wf);
  prep_state_kernel<<<1024, 256, 0, stream>>>(h0_a, h0_b, c0_a, c0_b, b_ih, b_hh,
                                              batch_a, batch_b, emb, bias, hb0, cb, xb0);
  u8* xb[2] = {xb0, xb1};
  u8* hb[2] = {hb0, hb1};
  for (int t = 0; t < 128; ++t) {
    lstm_step_kernel<<<512, 256, 0, stream>>>(batch_a, batch_b, emb, Wf, bias,
                                              xb[t & 1], xb[(t + 1) & 1],
                                              hb[t & 1], hb[(t + 1) & 1], cb, t);
  }
  finalize_kernel<<<128, 256, 0, stream>>>(hb[0], (float*)d_out);
}